// Round 3
// baseline (332.240 us; speedup 1.0000x reference)
//
#include <hip/hip_runtime.h>

// DynamicConv2d: B=16, CIN=COUT=64, K=3, H=W=192, OH=OW=190, DEG=64, HID=256
// out[b][co][oy][ox] = sum_{ci,ky,kx} w[b][co][ci][ky][kx] * x[b][ci][oy+ky][ox+kx]
// w = (relu(deg@W1+b1)@W2+b2).reshape(B,COUT,CIN,3,3)

typedef __bf16 bf16x8 __attribute__((ext_vector_type(8)));
typedef float  f32x4  __attribute__((ext_vector_type(4)));

#define NB   16
#define CIN  64
#define COUT 64
#define HW   192
#define OHW  190
#define NPIX (HW*HW)        // 36864
#define NW2  (COUT*CIN*9)   // 36864

__device__ __forceinline__ unsigned short f2bf(float f) {
    union { float f; unsigned int u; } v; v.f = f;
    unsigned int r = v.u + 0x7FFFu + ((v.u >> 16) & 1u);   // RNE
    return (unsigned short)(r >> 16);
}

// ---------------- k1: h = relu(deg @ W1 + b1)  [16,256] ----------------
__global__ void k1_hidden(const float* __restrict__ deg, const float* __restrict__ W1,
                          const float* __restrict__ b1, float* __restrict__ h) {
    int b = blockIdx.x, j = threadIdx.x;
    float acc = b1[j];
    for (int d = 0; d < 64; ++d) acc += deg[b*64 + d] * W1[d*256 + j];
    h[b*256 + j] = fmaxf(acc, 0.f);
}

// ---------------- k2: weights = h @ W2 + b2 -> Aw[b][tap][co][ci] bf16 ----------------
// grid 1152, block 256. Each block: 32 n-values x 8 k-chunks (32 k each) + LDS reduce.
__global__ void k2_wgen(const float* __restrict__ h, const float* __restrict__ W2,
                        const float* __restrict__ b2, unsigned short* __restrict__ Aw) {
    __shared__ float hs[16*256];
    __shared__ float red[8][16][33];
    int t = threadIdx.x;
    for (int i = t; i < 16*256; i += 256) hs[i] = h[i];
    __syncthreads();

    int nl = t & 31;                 // 0..31
    int kc = t >> 5;                 // 0..7
    int n  = blockIdx.x * 32 + nl;
    float acc[16] = {};
    #pragma unroll
    for (int kk = 0; kk < 32; ++kk) {
        int k = kc*32 + kk;
        float w = W2[(size_t)k*NW2 + n];
        #pragma unroll
        for (int b = 0; b < 16; ++b) acc[b] += hs[b*256 + k] * w;
    }
    #pragma unroll
    for (int b = 0; b < 16; ++b) red[kc][b][nl] = acc[b];
    __syncthreads();

    for (int i = t; i < 512; i += 256) {
        int b  = i >> 5;
        int nn = i & 31;
        int n2 = blockIdx.x * 32 + nn;
        float s = b2[n2];
        #pragma unroll
        for (int k = 0; k < 8; ++k) s += red[k][b][nn];
        // n2 = co*576 + ci*9 + tap   (reshape order COUT,CIN,3,3)
        int co  = n2 / 576;
        int rem = n2 - co*576;
        int ci  = rem / 9;
        int tap = rem - ci*9;
        Aw[(((b*9 + tap)*COUT + co)*CIN) + ci] = f2bf(s);
    }
}

// ---------------- k4: fused transpose + MFMA conv ----------------
// grid 4608 (6x * 48y * 16b), block 256 (4 waves). Tile: 64co x (4y x 32x).
// Staging fused from NCHW fp32: thread owns (pixel ps, ci-chunk c): 8 plane-strided
// coalesced fp32 loads -> cvt bf16 -> one ds_write_b128 at slot ps*8 + (c ^ (gx&7)).
// Read side uses the same XOR key -> bijective, conflict-free (measured 0 in R2).
// Waves: wv = (mh<<1)|rr : mh = co-half (32 co), rr = row-pair (2 rows).
#define TPIX (6*34)          // 204 pixels per tile (4+2 rows x 32+2 cols)
__global__ __launch_bounds__(256, 6)
void k4_conv(const float* __restrict__ x, const unsigned short* __restrict__ Aw,
             float* __restrict__ out) {
    __shared__ unsigned short xs[TPIX*8*8];   // 26112 B
    const int tid = threadIdx.x;

    // bijective XCD swizzle: 4608 % 8 == 0, 576 consecutive tiles per XCD
    int bid = blockIdx.x;
    int wg  = (bid & 7) * 576 + (bid >> 3);
    int b   = wg / 288;
    int rem = wg - b*288;
    int ty  = rem / 6;
    int tx  = rem - ty*6;
    const int x0 = tx * 32;
    const int y0 = ty * 4;

    // ---- fused staging: NCHW fp32 -> channels-last bf16 in LDS ----
    const float* xb = x + (size_t)b * CIN * NPIX;
    for (int it = 0; it < 7; ++it) {
        int s = it*256 + tid;
        if (s < TPIX*8) {
            int chunk = s / TPIX;          // ci chunk 0..7
            int ps    = s - chunk*TPIX;    // pixel 0..203
            int gyl = ps / 34;
            int gxl = ps - gyl*34;
            int gy = y0 + gyl; gy = gy > 191 ? 191 : gy;
            int gx = x0 + gxl; gx = gx > 191 ? 191 : gx;
            const float* src = xb + (size_t)(chunk*8)*NPIX + gy*HW + gx;
            float f[8];
            #pragma unroll
            for (int j = 0; j < 8; ++j) f[j] = src[(size_t)j*NPIX];
            union { bf16x8 v; unsigned short u[8]; } pk;
            #pragma unroll
            for (int j = 0; j < 8; ++j) pk.u[j] = f2bf(f[j]);
            int slot = ps*8 + (chunk ^ (gx & 7));
            *(bf16x8*)(&xs[slot*8]) = pk.v;
        }
    }
    __syncthreads();

    const int wv  = tid >> 6;
    const int mh  = wv >> 1;     // co half 0..1
    const int rr  = wv & 1;      // row pair 0..1
    const int l   = tid & 63;
    const int l15 = l & 15;
    const int lg  = l >> 4;      // 0..3

    f32x4 acc[2][4] = {};        // [m co-frag][n = r*2+xb]

    const unsigned short* Ab = Aw + b * (9*COUT*CIN);
    #pragma unroll
    for (int tap = 0; tap < 9; ++tap) {
        const int ky = tap / 3, kx = tap - 3*(tap/3);
        #pragma unroll
        for (int cc = 0; cc < 2; ++cc) {
            bf16x8 a[2], bb[4];
            #pragma unroll
            for (int m = 0; m < 2; ++m)
                a[m] = *(const bf16x8*)(Ab + tap*4096 + (mh*32 + m*16 + l15)*CIN + cc*32 + lg*8);
            #pragma unroll
            for (int r = 0; r < 2; ++r)
                #pragma unroll
                for (int xb2 = 0; xb2 < 2; ++xb2) {
                    int gyl = rr*2 + r + ky;
                    int gxl = xb2*16 + l15 + kx;
                    int pch = (cc*4 + lg) ^ (gxl & 7);
                    bb[r*2 + xb2] = *(const bf16x8*)(&xs[((gyl*34 + gxl)*8 + pch)*8]);
                }
            #pragma unroll
            for (int m = 0; m < 2; ++m)
                #pragma unroll
                for (int n = 0; n < 4; ++n)
                    acc[m][n] = __builtin_amdgcn_mfma_f32_16x16x32_bf16(a[m], bb[n], acc[m][n], 0, 0, 0);
        }
    }

    // ---- epilogue: D col = lane&15 (spatial), row = (lane>>4)*4+j (co) ----
    #pragma unroll
    for (int m = 0; m < 2; ++m)
        #pragma unroll
        for (int r = 0; r < 2; ++r)
            #pragma unroll
            for (int xb2 = 0; xb2 < 2; ++xb2) {
                int oy = y0 + rr*2 + r;
                int ox = x0 + xb2*16 + l15;
                if (oy < OHW && ox < OHW) {
                    f32x4 v = acc[m][r*2 + xb2];
                    #pragma unroll
                    for (int j = 0; j < 4; ++j) {
                        int co = mh*32 + m*16 + lg*4 + j;
                        out[((size_t)(b*COUT + co)*OHW + oy)*OHW + ox] = v[j];
                    }
                }
            }
}

extern "C" void kernel_launch(void* const* d_in, const int* in_sizes, int n_in,
                              void* d_out, int out_size, void* d_ws, size_t ws_size,
                              hipStream_t stream) {
    const float* x   = (const float*)d_in[0];
    const float* deg = (const float*)d_in[1];
    const float* W1  = (const float*)d_in[2];
    const float* b1  = (const float*)d_in[3];
    const float* W2  = (const float*)d_in[4];
    const float* b2  = (const float*)d_in[5];
    float* out = (float*)d_out;

    float* h           = (float*)d_ws;                       // 16 KB
    unsigned short* Aw = (unsigned short*)((char*)d_ws + 16*1024);  // 1.18 MB

    k1_hidden<<<16, 256, 0, stream>>>(deg, W1, b1, h);
    k2_wgen<<<NW2/32, 256, 0, stream>>>(h, W2, b2, Aw);
    k4_conv<<<4608, 256, 0, stream>>>(x, Aw, out);
}